// Round 1
// baseline (271.829 us; speedup 1.0000x reference)
//
#include <hip/hip_runtime.h>

// SSIM loss: 5 depthwise 11x11 Gaussian convs + SSIM map + global mean.
// Key insight: window = outer(g,g)/sum  => exactly separable. The normalized
// 1D kernel is recovered as the ROW SUMS of the provided 2D window (since
// sum_j w2d[i][j] = gn[i] when sum(gn)=1). Separable conv: 5x(11+11) taps
// instead of 5x121.

#define TX 32
#define TY 32
#define HALO 5
#define WSZ 11
#define LX (TX + 2 * HALO)      // 42
#define LY (TY + 2 * HALO)      // 42
#define LSTRIDE (LX + 1)        // 43 — break power-of-2-ish striding

__global__ void ssim_init(float* acc) {
    if (threadIdx.x == 0) acc[0] = 0.0f;
}

__global__ __launch_bounds__(256) void ssim_main(
    const float* __restrict__ x, const float* __restrict__ y,
    const float* __restrict__ w2d, float* __restrict__ acc,
    int H, int W)
{
    __shared__ float sx[LY][LSTRIDE];
    __shared__ float sy[LY][LSTRIDE];
    __shared__ float hx[LY][TX];
    __shared__ float hy[LY][TX];
    __shared__ float hxx[LY][TX];
    __shared__ float hyy[LY][TX];
    __shared__ float hxy[LY][TX];
    __shared__ float g[WSZ];
    __shared__ float wred[4];

    const int tid = threadIdx.x;

    // Recover normalized 1D kernel from 2D window (channel 0; all identical).
    if (tid < WSZ) {
        float s = 0.0f;
        #pragma unroll
        for (int j = 0; j < WSZ; ++j) s += w2d[tid * WSZ + j];
        g[tid] = s;
    }

    const int z = blockIdx.z;
    const float* __restrict__ xp = x + (size_t)z * H * W;
    const float* __restrict__ yp = y + (size_t)z * H * W;
    const int x0 = blockIdx.x * TX - HALO;
    const int y0 = blockIdx.y * TY - HALO;

    // Phase A: stage input tile + halo into LDS (zero-padded at borders).
    for (int idx = tid; idx < LY * LX; idx += 256) {
        const int r = idx / LX, c = idx - r * LX;
        const int gr = y0 + r, gc = x0 + c;
        float xv = 0.0f, yv = 0.0f;
        if (gr >= 0 && gr < H && gc >= 0 && gc < W) {
            const int o = gr * W + gc;
            xv = xp[o];
            yv = yp[o];
        }
        sx[r][c] = xv;
        sy[r][c] = yv;
    }
    __syncthreads();

    // Phase B: horizontal pass. 42 rows x 32 output cols, 5 quantities.
    for (int idx = tid; idx < LY * TX; idx += 256) {
        const int r = idx >> 5, c = idx & 31;
        float ax = 0.f, ay = 0.f, axx = 0.f, ayy = 0.f, axy = 0.f;
        #pragma unroll
        for (int k = 0; k < WSZ; ++k) {
            const float gv = g[k];
            const float xv = sx[r][c + k];
            const float yv = sy[r][c + k];
            ax  = fmaf(gv, xv, ax);
            ay  = fmaf(gv, yv, ay);
            axx = fmaf(gv, xv * xv, axx);
            ayy = fmaf(gv, yv * yv, ayy);
            axy = fmaf(gv, xv * yv, axy);
        }
        hx[r][c] = ax;  hy[r][c] = ay;
        hxx[r][c] = axx; hyy[r][c] = ayy; hxy[r][c] = axy;
    }
    __syncthreads();

    // Phase C: vertical pass + SSIM per pixel + thread-local accumulate.
    float lsum = 0.0f;
    for (int idx = tid; idx < TY * TX; idx += 256) {
        const int r = idx >> 5, c = idx & 31;
        float mx = 0.f, my = 0.f, sxx = 0.f, syy = 0.f, sxy = 0.f;
        #pragma unroll
        for (int k = 0; k < WSZ; ++k) {
            const float gv = g[k];
            mx  = fmaf(gv, hx[r + k][c], mx);
            my  = fmaf(gv, hy[r + k][c], my);
            sxx = fmaf(gv, hxx[r + k][c], sxx);
            syy = fmaf(gv, hyy[r + k][c], syy);
            sxy = fmaf(gv, hxy[r + k][c], sxy);
        }
        const float mx2 = mx * mx, my2 = my * my, mxy = mx * my;
        const float vx = sxx - mx2, vy = syy - my2, vxy = sxy - mxy;
        const float C1 = 1e-4f, C2 = 9e-4f;
        const float num = (2.0f * mxy + C1) * (2.0f * vxy + C2);
        const float den = (mx2 + my2 + C1) * (vx + vy + C2) + 1e-12f;
        lsum += num / den;
    }

    // Wave reduce (64 lanes), then cross-wave via LDS, one atomic per block.
    #pragma unroll
    for (int off = 32; off > 0; off >>= 1)
        lsum += __shfl_down(lsum, off, 64);
    const int lane = tid & 63, wave = tid >> 6;
    if (lane == 0) wred[wave] = lsum;
    __syncthreads();
    if (tid == 0) {
        atomicAdd(acc, wred[0] + wred[1] + wred[2] + wred[3]);
    }
}

__global__ void ssim_final(const float* __restrict__ acc,
                           float* __restrict__ out, float invN) {
    if (threadIdx.x == 0) out[0] = 1.0f - acc[0] * invN;
}

extern "C" void kernel_launch(void* const* d_in, const int* in_sizes, int n_in,
                              void* d_out, int out_size, void* d_ws, size_t ws_size,
                              hipStream_t stream) {
    const float* x   = (const float*)d_in[0];
    const float* y   = (const float*)d_in[1];
    const float* w2d = (const float*)d_in[2];  // (3,1,11,11); channels identical
    float* out = (float*)d_out;
    float* acc = (float*)d_ws;

    const int H = 512, W = 512;
    const int total = in_sizes[0];          // 16*3*512*512
    const int Z = total / (H * W);          // 48 images*channels

    ssim_init<<<1, 64, 0, stream>>>(acc);

    dim3 grid(W / TX, H / TY, Z);           // 16 x 16 x 48 = 12288 blocks
    ssim_main<<<grid, 256, 0, stream>>>(x, y, w2d, acc, H, W);

    const float invN = 1.0f / (float)total;
    ssim_final<<<1, 64, 0, stream>>>(acc, out, invN);
}